// Round 6
// baseline (2799.958 us; speedup 1.0000x reference)
//
#include <hip/hip_runtime.h>
#include <hip/hip_cooperative_groups.h>

namespace cg = cooperative_groups;

#define N_      800
#define C_      64
#define TRS_    40
#define SPT_    10
#define BUF_    120
#define T_      400
#define ROWS_   520           // taus -120..399, row = tau + 120 (time-major)
#define KPL     13            // edges per lane: 13*64 = 832 >= 800
#define SENT    0x7FC00BADu   // qNaN sentinel for "not yet written"
#define NEAR_D  16            // d < 16 -> LDS ring; d >= 16 -> far coalesced windows
#define DEPTH   16            // LDS ring depth (power of two)

#define A_F     (-0.5f)
#define OMEGA_F (10.0f)
#define G_F     (500.0f)
#define KGI_F   (5.0f)
#define DT_F    (1e-4f)

#define ALD(p)    __hip_atomic_load((p), __ATOMIC_RELAXED, __HIP_MEMORY_SCOPE_AGENT)
#define AST(p,v)  __hip_atomic_store((p), (v), __ATOMIC_RELAXED, __HIP_MEMORY_SCOPE_AGENT)

// ---------------- prelude kernels ----------------

__global__ void k_sumsq(const float* __restrict__ sc, float* __restrict__ sumsq) {
    __shared__ float sh[4];
    int tid = threadIdx.x;
    int idx = blockIdx.x * 256 + tid;
    float s = 0.f;
    for (int i = idx; i < N_ * N_; i += 256 * 256) { float v = sc[i]; s += v * v; }
    #pragma unroll
    for (int o = 1; o < 64; o <<= 1) s += __shfl_xor(s, o, 64);
    if ((tid & 63) == 0) sh[tid >> 6] = s;
    __syncthreads();
    if (tid == 0) atomicAdd(sumsq, sh[0] + sh[1] + sh[2] + sh[3]);
}

__global__ void k_detect(const int* __restrict__ dw, int* __restrict__ flag) {
    __shared__ int sh[4];
    int tid = threadIdx.x;
    int v = 0;
    for (int idx = 2 * tid + 1; idx < 800; idx += 512) v |= dw[idx];
    #pragma unroll
    for (int o = 1; o < 64; o <<= 1) v |= __shfl_xor(v, o, 64);
    if ((tid & 63) == 0) sh[tid >> 6] = v;
    __syncthreads();
    if (tid == 0) flag[0] = ((sh[0] | sh[1] | sh[2] | sh[3]) == 0) ? 1 : 0; // 1 => int64
}

// time-major history: row r = tau+120; rows [0,120) from hE, rows [120,520) = SENT
__global__ void k_init(const float* __restrict__ hE, unsigned int* __restrict__ xhT) {
    int idx = blockIdx.x * 256 + threadIdx.x;
    if (idx >= ROWS_ * N_) return;
    int r = idx / N_, j = idx - r * N_;
    unsigned int v = (r < 120) ? __float_as_uint(hE[j * BUF_ + (119 - r)]) : SENT;
    xhT[r * N_ + j] = v;
}

// ---------------- main persistent kernel ----------------

__global__ void __launch_bounds__(512, 1) k_main(
    const float* __restrict__ sc, const int* __restrict__ dw,
    const float* __restrict__ hx, const float* __restrict__ hE,
    const float* __restrict__ external, const float* __restrict__ noise,
    const float* __restrict__ lm,
    const float* __restrict__ sumsq, const int* __restrict__ flag,
    unsigned int* __restrict__ xhT, float* __restrict__ xtr, float* __restrict__ out)
{
    cg::grid_group grid = cg::this_grid();
    __shared__ float ring[DEPTH * N_];   // 51.2 KB, explicit

    const int tid  = threadIdx.x;
    const int lane = tid & 63;
    const int wid  = tid >> 6;
    const int i    = blockIdx.x * 8 + wid;   // row 0..799 (100 blocks x 8 waves)

    const float inv_norm = 1.0f / sqrtf(*sumsq);
    const int is64 = *flag;

    // ---- per-lane edge metadata ----
    float wn[KPL], wf[KPL]; int dnn[KPL], jb[KPL], f0[KPL];
    float rsum = 0.f;
    #pragma unroll
    for (int k = 0; k < KPL; ++k) {
        int j = k * 64 + lane;
        bool valid = (j < N_);
        int jj = valid ? j : 0;
        int base = i * N_ + jj;
        float wv = valid ? fabsf(sc[base]) * inv_norm : 0.f;
        int dv = valid ? dw[is64 ? (base << 1) : base] : 119;
        rsum += wv;
        bool nearc = valid && (dv < NEAR_D);
        bool farc  = valid && (dv >= NEAR_D);
        wn[k]  = nearc ? wv : 0.f;
        dnn[k] = nearc ? dv : 0;
        wf[k]  = farc  ? wv : 0.f;
        int dvf = farc ? dv : 119;
        f0[k]  = (119 - dvf) * N_ + jj;   // word addr of (tau = -1-d, j); +(t0+s)*N_ per step
        jb[k]  = jj;
    }
    #pragma unroll
    for (int o = 1; o < 64; o <<= 1) rsum += __shfl_xor(rsum, o, 64);

    float x = hx[2 * i], y = hx[2 * i + 1];   // uniform across the wave

    // ---- ring prefill: taus -16..-1; slot = tau & 15 => hE k2 = 15 - slot ----
    for (int slot = 0; slot < DEPTH; ++slot)
        for (int j = tid; j < N_; j += 512)
            ring[slot * N_ + j] = hE[j * BUF_ + (15 - slot)];
    __syncthreads();

    #pragma unroll 1
    for (int mb = 0; mb < 25; ++mb) {
        const int t0 = mb * 16;

        // ---- far prologue: coalesced cached column windows, accumulate fps[16] ----
        float fps[16];
        #pragma unroll
        for (int s = 0; s < 16; ++s) fps[s] = 0.f;

        #pragma unroll
        for (int k = 0; k < KPL; ++k) {
            int base = f0[k] + t0 * N_;
            float v[16];
            #pragma unroll
            for (int s = 0; s < 16; ++s)
                v[s] = __uint_as_float(xhT[base + s * N_]);   // cached, coalesced
            int g = 0;
            while (true) {
                int pend = 0;
                #pragma unroll
                for (int s = 0; s < 16; ++s)
                    pend |= (__float_as_uint(v[s]) == SENT) ? 1 : 0;
                if (!__any(pend)) break;
                if (++g > 2000000) break;     // safety valve (never expected)
                #pragma unroll
                for (int s = 0; s < 16; ++s)
                    if (__float_as_uint(v[s]) == SENT)
                        v[s] = __uint_as_float(ALD(&xhT[base + s * N_]));
            }
            float wk = wf[k];
            #pragma unroll
            for (int s = 0; s < 16; ++s) fps[s] += wk * v[s];
        }

        // ---- 16 integration steps ----
        #pragma unroll
        for (int s = 0; s < 16; ++s) {
            const int t = t0 + s;
            int tr = (t * 205) >> 11;         // t/10 for t<400
            int sp = t - tr * 10;
            float u  = external[(i * SPT_ + sp) * TRS_ + tr];
            float n0 = noise[(t * N_ + i) * 2 + 0];
            float n1 = noise[(t * N_ + i) * 2 + 1];

            // frontier: coalesced poll of row (t-1), then LDS ring publish
            if (t > 0) {
                const unsigned* fp = xhT + (t - 1 + 120) * N_;
                unsigned c0 = ALD(&fp[tid]);
                while (c0 == SENT) c0 = ALD(&fp[tid]);
                unsigned c1 = 0;
                if (tid < N_ - 512) {
                    c1 = ALD(&fp[512 + tid]);
                    while (c1 == SENT) c1 = ALD(&fp[512 + tid]);
                }
                float* rw = ring + ((t - 1) & 15) * N_;
                rw[tid] = __uint_as_float(c0);
                if (tid < N_ - 512) rw[512 + tid] = __uint_as_float(c1);
            }
            __syncthreads();

            // near gather from LDS ring (conflict-free: consecutive j per k)
            float acc = fps[s];
            #pragma unroll
            for (int k = 0; k < KPL; ++k) {
                int sl = (t - 1 - dnn[k]) & 15;
                acc += wn[k] * ring[sl * N_ + jb[k]];
            }
            #pragma unroll
            for (int o = 1; o < 64; o <<= 1) acc += __shfl_xor(acc, o, 64);

            float r2 = x * x + y * y;
            float dx = (A_F - r2) * x - OMEGA_F * y + G_F * (acc - rsum * x) + KGI_F * u;
            float dy = (A_F - r2) * y + OMEGA_F * x;
            x = x + DT_F * dx + n0;
            y = y + DT_F * dy + n1;

            if (lane == 0) {
                AST(&xhT[(t + 120) * N_ + i], __float_as_uint(x));
                if (sp == SPT_ - 1) xtr[tr * N_ + i] = x;
            }
        }
    }

    grid.sync();   // make xtr visible device-wide for the epilogue

    // epilogue: out[c*TRS + tr] = 5 * dot(xtr[tr,:], lm[c,:]) - 2
    for (int o = i; o < C_ * TRS_; o += 800) {
        int c = o / TRS_, tr = o - c * TRS_;
        float s = 0.f;
        #pragma unroll
        for (int k = 0; k < KPL; ++k) {
            int n = k * 64 + lane;
            if (n < N_) s += xtr[tr * N_ + n] * lm[c * N_ + n];
        }
        #pragma unroll
        for (int o2 = 1; o2 < 64; o2 <<= 1) s += __shfl_xor(s, o2, 64);
        if (lane == 0) out[o] = 5.0f * s - 2.0f;
    }
}

// ---------------- launch (proven shape: 100 x 512, ws <= R2's footprint) ----------------

extern "C" void kernel_launch(void* const* d_in, const int* in_sizes, int n_in,
                              void* d_out, int out_size, void* d_ws, size_t ws_size,
                              hipStream_t stream) {
    const float* external = (const float*)d_in[0];
    const float* hx       = (const float*)d_in[1];
    const float* hE       = (const float*)d_in[2];
    const float* sc       = (const float*)d_in[3];
    const float* lm       = (const float*)d_in[4];
    const float* noise    = (const float*)d_in[5];
    const int*   delays   = (const int*)  d_in[6];
    float* out = (float*)d_out;

    float*        sumsq = (float*)d_ws;                    // ws[0]
    int*          flag  = (int*)d_ws + 1;                  // ws[1]
    unsigned int* xhT   = (unsigned int*)d_ws + 64;        // 520*800 words (1.664 MB)
    float*        xtr   = (float*)(xhT + ROWS_ * N_);      // 40*800 floats (0.128 MB)

    hipMemsetAsync(d_ws, 0, 8, stream);
    k_sumsq<<<256, 256, 0, stream>>>(sc, sumsq);
    k_detect<<<1, 256, 0, stream>>>(delays, flag);
    k_init<<<(ROWS_ * N_ + 255) / 256, 256, 0, stream>>>(hE, xhT);

    void* args[] = { (void*)&sc, (void*)&delays, (void*)&hx, (void*)&hE,
                     (void*)&external, (void*)&noise, (void*)&lm,
                     (void*)&sumsq, (void*)&flag,
                     (void*)&xhT, (void*)&xtr, (void*)&out };
    hipLaunchCooperativeKernel((const void*)k_main, dim3(100), dim3(512), args, 0, stream);
}